// Round 6
// baseline (547.318 us; speedup 1.0000x reference)
//
#include <hip/hip_runtime.h>
#include <hip/hip_bf16.h>
#include <stdint.h>

#define NN   100000
#define ICH  256
#define HID  128
#define OUTF 64

typedef float  f32x4  __attribute__((ext_vector_type(4)));
typedef __bf16 bf16x8 __attribute__((ext_vector_type(8)));

__device__ __forceinline__ float bf2f(uint16_t u){
  union { uint32_t i; float f; } v; v.i = ((uint32_t)u) << 16; return v.f;
}
__device__ __forceinline__ uint16_t f2bf(float f){
  union { float f; uint32_t i; } v; v.f = f;
  uint32_t i = v.i;
  return (uint16_t)((i + 0x7FFFu + ((i >> 16) & 1u)) >> 16);
}
__device__ __forceinline__ uint32_t pack2(float a, float b){
  return (uint32_t)f2bf(a) | ((uint32_t)f2bf(b) << 16);
}

// Fused CSR build: edges sorted by src. rp[i] + r[i] = 1/(deg_i+1).
__global__ void k_csr(const int* __restrict__ row, int E, int n,
                      int* __restrict__ rp, float* __restrict__ r){
  int i = blockIdx.x * blockDim.x + threadIdx.x;
  if (i > n) return;
  int lo = 0, hi = E;
  while (lo < hi){
    int mid = (lo + hi) >> 1;
    if (row[mid] < i) lo = mid + 1; else hi = mid;
  }
  rp[i] = lo;
  if (i < n){
    int lo2 = lo, hi2 = E;
    while (lo2 < hi2){
      int mid = (lo2 + hi2) >> 1;
      if (row[mid] < i + 1) lo2 = mid + 1; else hi2 = mid;
    }
    r[i] = 1.0f / (float)(lo2 - lo + 1);
  }
}

// bf16-transpose weights: W1T/W2T [l][n][k], Wl1T [n][k] (k<256), Wl2T [n][k]
__global__ void k_wprep(const float* __restrict__ W1, const float* __restrict__ W2,
                        const float* __restrict__ Wl1, const float* __restrict__ Wl2,
                        uint16_t* __restrict__ W1T, uint16_t* __restrict__ W2T,
                        uint16_t* __restrict__ Wl1T, uint16_t* __restrict__ Wl2T){
  int idx = blockIdx.x * blockDim.x + threadIdx.x;
  if (idx < 4 * 128 * 128){
    int l = idx >> 14, rem = idx & 16383, n = rem >> 7, k = rem & 127;
    W1T[idx] = f2bf(W1[l * 16384 + k * 128 + n]);
    W2T[idx] = f2bf(W2[l * 16384 + k * 128 + n]);
  }
  if (idx < 128 * 256){
    int n = idx >> 8, k = idx & 255;
    Wl1T[idx] = f2bf(Wl1[k * 128 + n]);
  }
  if (idx < 64 * 128){
    int n = idx >> 7, k = idx & 127;
    Wl2T[idx] = f2bf(Wl2[k * 64 + n]);
  }
}

// h = relu(x @ W_lin1 + b) via MFMA. 64-node tile, wave w owns cols [32w,32w+32).
__launch_bounds__(256)
__global__ void k_lin1m(const float* __restrict__ x, const uint16_t* __restrict__ Wl1T,
                        const float* __restrict__ b, uint16_t* __restrict__ h){
  __shared__ __align__(16) uint16_t Xs[64][264];   // 256 + 8 pad
  const int tid = threadIdx.x;
  const int node0 = blockIdx.x * 64;
  const int wv = tid >> 6, lane = tid & 63, lr = lane & 15, lg = lane >> 4;

  #pragma unroll
  for (int i = 0; i < 16; ++i){
    int fi = tid + i * 256;
    int rrow = fi >> 6, c4 = (fi & 63) * 4;
    int nd = node0 + rrow;
    float4 f = (nd < NN) ? *(const float4*)(x + (size_t)nd * ICH + c4)
                         : make_float4(0.f, 0.f, 0.f, 0.f);
    *(uint2*)&Xs[rrow][c4] = make_uint2(pack2(f.x, f.y), pack2(f.z, f.w));
  }
  __syncthreads();

  bf16x8 bfr[2][8];
  #pragma unroll
  for (int n2 = 0; n2 < 2; ++n2){
    const int n = (2 * wv + n2) * 16 + lr;
    const uint16_t* bp = Wl1T + (size_t)n * 256 + lg * 8;
    #pragma unroll
    for (int ks = 0; ks < 8; ++ks)
      bfr[n2][ks] = __builtin_bit_cast(bf16x8, *(const uint4*)(bp + ks * 32));
  }
  float bias[2] = {b[(2 * wv + 0) * 16 + lr], b[(2 * wv + 1) * 16 + lr]};

  #pragma unroll
  for (int rt = 0; rt < 4; ++rt){
    const int row = rt * 16 + lr;
    bf16x8 af[8];
    #pragma unroll
    for (int ks = 0; ks < 8; ++ks)
      af[ks] = __builtin_bit_cast(bf16x8, *(const uint4*)&Xs[row][ks * 32 + lg * 8]);
    #pragma unroll
    for (int n2 = 0; n2 < 2; ++n2){
      f32x4 d = (f32x4){0.f, 0.f, 0.f, 0.f};
      #pragma unroll
      for (int ks = 0; ks < 8; ++ks)
        d = __builtin_amdgcn_mfma_f32_16x16x32_bf16(af[ks], bfr[n2][ks], d, 0, 0, 0);
      const int ncol = (2 * wv + n2) * 16 + lr;
      #pragma unroll
      for (int q = 0; q < 4; ++q){
        int nd = node0 + rt * 16 + lg * 4 + q;
        if (nd < NN){
          float v = d[q] + bias[n2];
          h[(size_t)nd * HID + ncol] = f2bf(v > 0.f ? v : 0.f);
        }
      }
    }
  }
}

// one wave per node: P = S h, T1 = S(r.h), T2 = S(r^2.h)
__launch_bounds__(256)
__global__ void k_spmmA(const int* __restrict__ col, const int* __restrict__ rp,
                        const float* __restrict__ r, const uint32_t* __restrict__ h,
                        uint32_t* __restrict__ P, uint32_t* __restrict__ T1,
                        uint32_t* __restrict__ T2){
  int wid  = (blockIdx.x * blockDim.x + threadIdx.x) >> 6;
  int lane = threadIdx.x & 63;
  if (wid >= NN) return;
  int e0 = rp[wid], e1 = rp[wid + 1];
  float a0 = 0, b0 = 0, a1 = 0, b1 = 0, a2 = 0, b2 = 0;
  for (int base = e0; base < e1; base += 64){
    int tot = e1 - base;
    int cnt = tot < 64 ? tot : 64;
    int jv  = (lane < cnt) ? col[base + lane] : 0;
    int rvb = (lane < cnt) ? __builtin_bit_cast(int, r[jv]) : 0;
    int k = 0;
    for (; k + 16 <= cnt; k += 16){
      uint32_t hv[16];
      #pragma unroll
      for (int t = 0; t < 16; ++t){
        int j = __builtin_amdgcn_readlane(jv, k + t);
        hv[t] = h[((uint32_t)j << 6) + lane];
      }
      #pragma unroll
      for (int t = 0; t < 16; ++t){
        float rj = __builtin_bit_cast(float, __builtin_amdgcn_readlane(rvb, k + t));
        float r2 = rj * rj;
        float x0 = __builtin_bit_cast(float, hv[t] << 16);
        float x1 = __builtin_bit_cast(float, hv[t] & 0xFFFF0000u);
        a0 += x0;               b0 += x1;
        a1 = fmaf(rj, x0, a1);  b1 = fmaf(rj, x1, b1);
        a2 = fmaf(r2, x0, a2);  b2 = fmaf(r2, x1, b2);
      }
    }
    for (; k + 4 <= cnt; k += 4){
      uint32_t hv[4];
      #pragma unroll
      for (int t = 0; t < 4; ++t){
        int j = __builtin_amdgcn_readlane(jv, k + t);
        hv[t] = h[((uint32_t)j << 6) + lane];
      }
      #pragma unroll
      for (int t = 0; t < 4; ++t){
        float rj = __builtin_bit_cast(float, __builtin_amdgcn_readlane(rvb, k + t));
        float r2 = rj * rj;
        float x0 = __builtin_bit_cast(float, hv[t] << 16);
        float x1 = __builtin_bit_cast(float, hv[t] & 0xFFFF0000u);
        a0 += x0;               b0 += x1;
        a1 = fmaf(rj, x0, a1);  b1 = fmaf(rj, x1, b1);
        a2 = fmaf(r2, x0, a2);  b2 = fmaf(r2, x1, b2);
      }
    }
    for (; k < cnt; ++k){
      int j = __builtin_amdgcn_readlane(jv, k);
      float rj = __builtin_bit_cast(float, __builtin_amdgcn_readlane(rvb, k));
      float r2 = rj * rj;
      uint32_t hv = h[((uint32_t)j << 6) + lane];
      float x0 = __builtin_bit_cast(float, hv << 16);
      float x1 = __builtin_bit_cast(float, hv & 0xFFFF0000u);
      a0 += x0;               b0 += x1;
      a1 = fmaf(rj, x0, a1);  b1 = fmaf(rj, x1, b1);
      a2 = fmaf(r2, x0, a2);  b2 = fmaf(r2, x1, b2);
    }
  }
  size_t o = (size_t)wid * 64 + lane;
  P[o]  = pack2(a0, b0);
  T1[o] = pack2(a1, b1);
  T2[o] = pack2(a2, b2);
}

// Q1 = S(r.P), Q2 = S(r^2.P)
__launch_bounds__(256)
__global__ void k_spmmB(const int* __restrict__ col, const int* __restrict__ rp,
                        const float* __restrict__ r, const uint32_t* __restrict__ Pm,
                        uint32_t* __restrict__ Q1, uint32_t* __restrict__ Q2){
  int wid  = (blockIdx.x * blockDim.x + threadIdx.x) >> 6;
  int lane = threadIdx.x & 63;
  if (wid >= NN) return;
  int e0 = rp[wid], e1 = rp[wid + 1];
  float a1 = 0, b1 = 0, a2 = 0, b2 = 0;
  for (int base = e0; base < e1; base += 64){
    int tot = e1 - base;
    int cnt = tot < 64 ? tot : 64;
    int jv  = (lane < cnt) ? col[base + lane] : 0;
    int rvb = (lane < cnt) ? __builtin_bit_cast(int, r[jv]) : 0;
    int k = 0;
    for (; k + 16 <= cnt; k += 16){
      uint32_t pv[16];
      #pragma unroll
      for (int t = 0; t < 16; ++t){
        int j = __builtin_amdgcn_readlane(jv, k + t);
        pv[t] = Pm[((uint32_t)j << 6) + lane];
      }
      #pragma unroll
      for (int t = 0; t < 16; ++t){
        float rj = __builtin_bit_cast(float, __builtin_amdgcn_readlane(rvb, k + t));
        float r2 = rj * rj;
        float x0 = __builtin_bit_cast(float, pv[t] << 16);
        float x1 = __builtin_bit_cast(float, pv[t] & 0xFFFF0000u);
        a1 = fmaf(rj, x0, a1);  b1 = fmaf(rj, x1, b1);
        a2 = fmaf(r2, x0, a2);  b2 = fmaf(r2, x1, b2);
      }
    }
    for (; k + 4 <= cnt; k += 4){
      uint32_t pv[4];
      #pragma unroll
      for (int t = 0; t < 4; ++t){
        int j = __builtin_amdgcn_readlane(jv, k + t);
        pv[t] = Pm[((uint32_t)j << 6) + lane];
      }
      #pragma unroll
      for (int t = 0; t < 4; ++t){
        float rj = __builtin_bit_cast(float, __builtin_amdgcn_readlane(rvb, k + t));
        float r2 = rj * rj;
        float x0 = __builtin_bit_cast(float, pv[t] << 16);
        float x1 = __builtin_bit_cast(float, pv[t] & 0xFFFF0000u);
        a1 = fmaf(rj, x0, a1);  b1 = fmaf(rj, x1, b1);
        a2 = fmaf(r2, x0, a2);  b2 = fmaf(r2, x1, b2);
      }
    }
    for (; k < cnt; ++k){
      int j = __builtin_amdgcn_readlane(jv, k);
      float rj = __builtin_bit_cast(float, __builtin_amdgcn_readlane(rvb, k));
      float r2 = rj * rj;
      uint32_t pv = Pm[((uint32_t)j << 6) + lane];
      float x0 = __builtin_bit_cast(float, pv << 16);
      float x1 = __builtin_bit_cast(float, pv & 0xFFFF0000u);
      a1 = fmaf(rj, x0, a1);  b1 = fmaf(rj, x1, b1);
      a2 = fmaf(r2, x0, a2);  b2 = fmaf(r2, x1, b2);
    }
  }
  size_t o = (size_t)wid * 64 + lane;
  Q1[o] = pack2(a1, b1);
  Q2[o] = pack2(a2, b2);
}

__device__ __forceinline__ void ld4u(const uint32_t* p, uint32_t a[4]){
  uint4 t = *(const uint4*)p;
  a[0] = t.x; a[1] = t.y; a[2] = t.z; a[3] = t.w;
}

// Register-built MFMA epilogue: wave w owns rows [16w,16w+16) x all 128 cols.
// Per layer: each lane loads its OWN row's 16B chunks of h/P/T/Q straight from
// global, builds M1/M2 A-fragments in registers, runs MFMA vs W from global
// (all waves read same W frags -> L1 hits). No LDS / no barriers in main loop.
__launch_bounds__(256)
__global__ void k_epi3(const uint32_t* __restrict__ h,  const uint32_t* __restrict__ P,
                       const uint32_t* __restrict__ T1, const uint32_t* __restrict__ T2,
                       const uint32_t* __restrict__ Q1, const uint32_t* __restrict__ Q2,
                       const float* __restrict__ r,
                       const uint16_t* __restrict__ W1T, const uint16_t* __restrict__ W2T,
                       const uint16_t* __restrict__ Wl2T, const float* __restrict__ b2,
                       float* __restrict__ out){
  __shared__ __align__(16) uint32_t Mu[64][68];    // lin2 transpose stage only
  const int tid = threadIdx.x;
  const int node0 = blockIdx.x * 64;
  const int wv = tid >> 6, lane = tid & 63, lr = lane & 15, lg = lane >> 4;

  const int rowA = node0 + wv * 16 + lr;           // A-row this lane builds
  const int rn = rowA < NN ? rowA : NN - 1;        // clamp (garbage rows masked at store)
  const float rv = r[rn];
  const size_t ub = (size_t)rn * 64;               // uint32 row base

  f32x4 acc[8];
  #pragma unroll
  for (int nt = 0; nt < 8; ++nt) acc[nt] = (f32x4){0.f, 0.f, 0.f, 0.f};

  #pragma unroll
  for (int l = 0; l < 4; ++l){
    // ---- build A-fragments for M1,M2 in registers ----
    uint4 m1f[4], m2f[4];
    #pragma unroll
    for (int ks = 0; ks < 4; ++ks){
      const int uo = ks * 16 + lg * 4;
      uint32_t ah[4], ap[4], at1[4], at2[4], aq1[4], aq2[4];
      ld4u(h + ub + uo, ah);
      ld4u(P + ub + uo, ap);
      if (l == 1){ ld4u(Q1 + ub + uo, aq1); ld4u(T1 + ub + uo, at1); }
      if (l == 2){ ld4u(Q2 + ub + uo, aq2); ld4u(T1 + ub + uo, at1); ld4u(T2 + ub + uo, at2); }
      uint32_t o1[4], o2[4];
      #pragma unroll
      for (int w = 0; w < 4; ++w){
        float m1s[2], m2s[2];
        #pragma unroll
        for (int s = 0; s < 2; ++s){
          float hh = bf2f((uint16_t)(s ? (ah[w] >> 16) : ah[w]));
          float pp = bf2f((uint16_t)(s ? (ap[w] >> 16) : ap[w]));
          if (l == 0){
            float F = rv * (pp + hh);
            m1s[s] = F; m2s[s] = hh - F;
          } else if (l == 1){
            float t1 = bf2f((uint16_t)(s ? (at1[w] >> 16) : at1[w]));
            float q1 = bf2f((uint16_t)(s ? (aq1[w] >> 16) : aq1[w]));
            float F = rv * (pp + hh);
            float G = hh - F;
            m1s[s] = rv * (pp - q1 - t1 + G);
            m2s[s] = F - rv * (q1 + t1 + F);
          } else if (l == 2){
            float t1 = bf2f((uint16_t)(s ? (at1[w] >> 16) : at1[w]));
            float t2 = bf2f((uint16_t)(s ? (at2[w] >> 16) : at2[w]));
            float q2 = bf2f((uint16_t)(s ? (aq2[w] >> 16) : aq2[w]));
            float omr = 1.f - rv;
            float G2 = rv * rv * pp + omr * omr * hh;
            m1s[s] = rv * (q2 + pp - 2.f * t1 + t2 + G2);
            float F2 = rv * rv * (pp + hh);
            m2s[s] = F2 - rv * (q2 + t2 + F2);
          } else {
            float omr = 1.f - rv;
            float r3 = rv * rv * rv;
            m1s[s] = omr * omr * omr * hh - r3 * pp;
            m2s[s] = r3 * (pp + hh);
          }
        }
        o1[w] = pack2(m1s[0], m1s[1]);
        o2[w] = pack2(m2s[0], m2s[1]);
      }
      m1f[ks] = make_uint4(o1[0], o1[1], o1[2], o1[3]);
      m2f[ks] = make_uint4(o2[0], o2[1], o2[2], o2[3]);
    }

    // ---- MFMA: acc += relu(M @ W), M1/W1 then M2/W2 ----
    #pragma unroll
    for (int m = 0; m < 2; ++m){
      const uint16_t* Wt = (m ? W2T : W1T) + (size_t)l * 128 * 128;
      const uint4* mf = m ? m2f : m1f;
      #pragma unroll
      for (int nt = 0; nt < 8; ++nt){
        const uint16_t* bp = Wt + (size_t)(nt * 16 + lr) * 128 + lg * 8;
        f32x4 d = (f32x4){0.f, 0.f, 0.f, 0.f};
        #pragma unroll
        for (int ks = 0; ks < 4; ++ks){
          bf16x8 bfr = __builtin_bit_cast(bf16x8, *(const uint4*)(bp + ks * 32));
          d = __builtin_amdgcn_mfma_f32_16x16x32_bf16(
                __builtin_bit_cast(bf16x8, mf[ks]), bfr, d, 0, 0, 0);
        }
        #pragma unroll
        for (int q = 0; q < 4; ++q)
          acc[nt][q] += (d[q] > 0.f ? d[q] : 0.f);
      }
    }
  }

  // ---- lin2: stage acc/8 as bf16 in LDS (transpose), then 64x128x64 MFMA ----
  uint16_t* Mb = (uint16_t*)&Mu[0][0];             // row stride 136 bf16
  #pragma unroll
  for (int nt = 0; nt < 8; ++nt)
    #pragma unroll
    for (int q = 0; q < 4; ++q){
      int row = wv * 16 + lg * 4 + q;
      int colb = nt * 16 + lr;
      Mb[row * 136 + colb] = f2bf(acc[nt][q] * 0.125f);
    }
  __syncthreads();

  const int arow = 16 * wv + lr;
  bf16x8 af2[4];
  #pragma unroll
  for (int ks = 0; ks < 4; ++ks)
    af2[ks] = __builtin_bit_cast(bf16x8, *(const uint4*)&Mu[arow][ks * 16 + lg * 4]);
  #pragma unroll
  for (int nt = 0; nt < 4; ++nt){
    f32x4 d = (f32x4){0.f, 0.f, 0.f, 0.f};
    #pragma unroll
    for (int ks = 0; ks < 4; ++ks){
      bf16x8 bfr = __builtin_bit_cast(bf16x8,
          *(const uint4*)(Wl2T + (size_t)(nt * 16 + lr) * 128 + ks * 32 + lg * 8));
      d = __builtin_amdgcn_mfma_f32_16x16x32_bf16(af2[ks], bfr, d, 0, 0, 0);
    }
    float bias = b2[nt * 16 + lr];
    #pragma unroll
    for (int q = 0; q < 4; ++q){
      int rr = node0 + 16 * wv + lg * 4 + q;
      if (rr < NN) out[(size_t)rr * OUTF + nt * 16 + lr] = d[q] + bias;
    }
  }
}

extern "C" void kernel_launch(void* const* d_in, const int* in_sizes, int n_in,
                              void* d_out, int out_size, void* d_ws, size_t ws_size,
                              hipStream_t stream){
  const float* x   = (const float*)d_in[0];
  const float* Wl1 = (const float*)d_in[1];
  const float* bl1 = (const float*)d_in[2];
  const float* W1  = (const float*)d_in[3];
  const float* W2  = (const float*)d_in[4];
  const float* Wl2 = (const float*)d_in[5];
  const float* bl2 = (const float*)d_in[6];
  const int*   ei  = (const int*)d_in[7];
  int E = in_sizes[7] / 2;
  const int* rowp = ei;
  const int* colp = ei + E;

  char* ws = (char*)d_ws;
  size_t off = 0;
  auto alloc = [&](size_t bytes) -> void* {
    void* p = ws + off;
    off += (bytes + 255) & ~(size_t)255;
    return p;
  };
  const size_t MATB = (size_t)NN * HID * 2;
  uint32_t* h  = (uint32_t*)alloc(MATB);
  uint32_t* P  = (uint32_t*)alloc(MATB);
  uint32_t* T1 = (uint32_t*)alloc(MATB);
  uint32_t* T2 = (uint32_t*)alloc(MATB);
  uint32_t* Q1 = (uint32_t*)alloc(MATB);
  uint32_t* Q2 = (uint32_t*)alloc(MATB);
  float* r  = (float*)alloc((size_t)NN * 4);
  int* rp   = (int*)alloc((size_t)(NN + 1) * 4);
  uint16_t* W1T  = (uint16_t*)alloc((size_t)4 * 128 * 128 * 2);
  uint16_t* W2T  = (uint16_t*)alloc((size_t)4 * 128 * 128 * 2);
  uint16_t* Wl1T = (uint16_t*)alloc((size_t)128 * 256 * 2);
  uint16_t* Wl2T = (uint16_t*)alloc((size_t)64 * 128 * 2);

  k_wprep<<<(4 * 128 * 128 + 255) / 256, 256, 0, stream>>>(W1, W2, Wl1, Wl2,
                                                           W1T, W2T, Wl1T, Wl2T);
  k_csr<<<(NN + 1 + 255) / 256, 256, 0, stream>>>(rowp, E, NN, rp, r);
  k_lin1m<<<(NN + 63) / 64, 256, 0, stream>>>(x, Wl1T, bl1, (uint16_t*)h);
  k_spmmA<<<(NN + 3) / 4, 256, 0, stream>>>(colp, rp, r, h, P, T1, T2);
  k_spmmB<<<(NN + 3) / 4, 256, 0, stream>>>(colp, rp, r, P, Q1, Q2);
  k_epi3<<<(NN + 63) / 64, 256, 0, stream>>>(h, P, T1, T2, Q1, Q2, r,
                                             W1T, W2T, Wl2T, bl2, (float*)d_out);
}

// Round 7
// 507.645 us; speedup vs baseline: 1.0782x; 1.0782x over previous
//
#include <hip/hip_runtime.h>
#include <hip/hip_bf16.h>
#include <stdint.h>

#define NN   100000
#define ICH  256
#define HID  128
#define OUTF 64

typedef float  f32x4  __attribute__((ext_vector_type(4)));
typedef __bf16 bf16x8 __attribute__((ext_vector_type(8)));

__device__ __forceinline__ float bf2f(uint16_t u){
  union { uint32_t i; float f; } v; v.i = ((uint32_t)u) << 16; return v.f;
}
__device__ __forceinline__ uint16_t f2bf(float f){
  union { float f; uint32_t i; } v; v.f = f;
  uint32_t i = v.i;
  return (uint16_t)((i + 0x7FFFu + ((i >> 16) & 1u)) >> 16);
}
__device__ __forceinline__ uint32_t pack2(float a, float b){
  return (uint32_t)f2bf(a) | ((uint32_t)f2bf(b) << 16);
}

// Fused CSR build: edges sorted by src. rp[i] + r[i] = 1/(deg_i+1).
__global__ void k_csr(const int* __restrict__ row, int E, int n,
                      int* __restrict__ rp, float* __restrict__ r){
  int i = blockIdx.x * blockDim.x + threadIdx.x;
  if (i > n) return;
  int lo = 0, hi = E;
  while (lo < hi){
    int mid = (lo + hi) >> 1;
    if (row[mid] < i) lo = mid + 1; else hi = mid;
  }
  rp[i] = lo;
  if (i < n){
    int lo2 = lo, hi2 = E;
    while (lo2 < hi2){
      int mid = (lo2 + hi2) >> 1;
      if (row[mid] < i + 1) lo2 = mid + 1; else hi2 = mid;
    }
    r[i] = 1.0f / (float)(lo2 - lo + 1);
  }
}

// bf16-transpose weights: W1T/W2T [l][n][k], Wl1T [n][k] (k<256), Wl2T [n][k]
__global__ void k_wprep(const float* __restrict__ W1, const float* __restrict__ W2,
                        const float* __restrict__ Wl1, const float* __restrict__ Wl2,
                        uint16_t* __restrict__ W1T, uint16_t* __restrict__ W2T,
                        uint16_t* __restrict__ Wl1T, uint16_t* __restrict__ Wl2T){
  int idx = blockIdx.x * blockDim.x + threadIdx.x;
  if (idx < 4 * 128 * 128){
    int l = idx >> 14, rem = idx & 16383, n = rem >> 7, k = rem & 127;
    W1T[idx] = f2bf(W1[l * 16384 + k * 128 + n]);
    W2T[idx] = f2bf(W2[l * 16384 + k * 128 + n]);
  }
  if (idx < 128 * 256){
    int n = idx >> 8, k = idx & 255;
    Wl1T[idx] = f2bf(Wl1[k * 128 + n]);
  }
  if (idx < 64 * 128){
    int n = idx >> 7, k = idx & 127;
    Wl2T[idx] = f2bf(Wl2[k * 64 + n]);
  }
}

// h = relu(x @ W_lin1 + b) via MFMA. 64-node tile, wave w owns cols [32w,32w+32).
__launch_bounds__(256)
__global__ void k_lin1m(const float* __restrict__ x, const uint16_t* __restrict__ Wl1T,
                        const float* __restrict__ b, uint16_t* __restrict__ h){
  __shared__ __align__(16) uint16_t Xs[64][264];   // 256 + 8 pad
  const int tid = threadIdx.x;
  const int node0 = blockIdx.x * 64;
  const int wv = tid >> 6, lane = tid & 63, lr = lane & 15, lg = lane >> 4;

  #pragma unroll
  for (int i = 0; i < 16; ++i){
    int fi = tid + i * 256;
    int rrow = fi >> 6, c4 = (fi & 63) * 4;
    int nd = node0 + rrow;
    float4 f = (nd < NN) ? *(const float4*)(x + (size_t)nd * ICH + c4)
                         : make_float4(0.f, 0.f, 0.f, 0.f);
    *(uint2*)&Xs[rrow][c4] = make_uint2(pack2(f.x, f.y), pack2(f.z, f.w));
  }
  __syncthreads();

  bf16x8 bfr[2][8];
  #pragma unroll
  for (int n2 = 0; n2 < 2; ++n2){
    const int n = (2 * wv + n2) * 16 + lr;
    const uint16_t* bp = Wl1T + (size_t)n * 256 + lg * 8;
    #pragma unroll
    for (int ks = 0; ks < 8; ++ks)
      bfr[n2][ks] = __builtin_bit_cast(bf16x8, *(const uint4*)(bp + ks * 32));
  }
  float bias[2] = {b[(2 * wv + 0) * 16 + lr], b[(2 * wv + 1) * 16 + lr]};

  #pragma unroll
  for (int rt = 0; rt < 4; ++rt){
    const int row = rt * 16 + lr;
    bf16x8 af[8];
    #pragma unroll
    for (int ks = 0; ks < 8; ++ks)
      af[ks] = __builtin_bit_cast(bf16x8, *(const uint4*)&Xs[row][ks * 32 + lg * 8]);
    #pragma unroll
    for (int n2 = 0; n2 < 2; ++n2){
      f32x4 d = (f32x4){0.f, 0.f, 0.f, 0.f};
      #pragma unroll
      for (int ks = 0; ks < 8; ++ks)
        d = __builtin_amdgcn_mfma_f32_16x16x32_bf16(af[ks], bfr[n2][ks], d, 0, 0, 0);
      const int ncol = (2 * wv + n2) * 16 + lr;
      #pragma unroll
      for (int q = 0; q < 4; ++q){
        int nd = node0 + rt * 16 + lg * 4 + q;
        if (nd < NN){
          float v = d[q] + bias[n2];
          h[(size_t)nd * HID + ncol] = f2bf(v > 0.f ? v : 0.f);
        }
      }
    }
  }
}

// one wave per node: P = S h, T1 = S(r.h), T2 = S(r^2.h)
__launch_bounds__(256)
__global__ void k_spmmA(const int* __restrict__ col, const int* __restrict__ rp,
                        const float* __restrict__ r, const uint32_t* __restrict__ h,
                        uint32_t* __restrict__ P, uint32_t* __restrict__ T1,
                        uint32_t* __restrict__ T2){
  int wid  = (blockIdx.x * blockDim.x + threadIdx.x) >> 6;
  int lane = threadIdx.x & 63;
  if (wid >= NN) return;
  int e0 = rp[wid], e1 = rp[wid + 1];
  float a0 = 0, b0 = 0, a1 = 0, b1 = 0, a2 = 0, b2 = 0;
  for (int base = e0; base < e1; base += 64){
    int tot = e1 - base;
    int cnt = tot < 64 ? tot : 64;
    int jv  = (lane < cnt) ? col[base + lane] : 0;
    int rvb = (lane < cnt) ? __builtin_bit_cast(int, r[jv]) : 0;
    int k = 0;
    for (; k + 16 <= cnt; k += 16){
      uint32_t hv[16];
      #pragma unroll
      for (int t = 0; t < 16; ++t){
        int j = __builtin_amdgcn_readlane(jv, k + t);
        hv[t] = h[((uint32_t)j << 6) + lane];
      }
      #pragma unroll
      for (int t = 0; t < 16; ++t){
        float rj = __builtin_bit_cast(float, __builtin_amdgcn_readlane(rvb, k + t));
        float r2 = rj * rj;
        float x0 = __builtin_bit_cast(float, hv[t] << 16);
        float x1 = __builtin_bit_cast(float, hv[t] & 0xFFFF0000u);
        a0 += x0;               b0 += x1;
        a1 = fmaf(rj, x0, a1);  b1 = fmaf(rj, x1, b1);
        a2 = fmaf(r2, x0, a2);  b2 = fmaf(r2, x1, b2);
      }
    }
    for (; k + 4 <= cnt; k += 4){
      uint32_t hv[4];
      #pragma unroll
      for (int t = 0; t < 4; ++t){
        int j = __builtin_amdgcn_readlane(jv, k + t);
        hv[t] = h[((uint32_t)j << 6) + lane];
      }
      #pragma unroll
      for (int t = 0; t < 4; ++t){
        float rj = __builtin_bit_cast(float, __builtin_amdgcn_readlane(rvb, k + t));
        float r2 = rj * rj;
        float x0 = __builtin_bit_cast(float, hv[t] << 16);
        float x1 = __builtin_bit_cast(float, hv[t] & 0xFFFF0000u);
        a0 += x0;               b0 += x1;
        a1 = fmaf(rj, x0, a1);  b1 = fmaf(rj, x1, b1);
        a2 = fmaf(r2, x0, a2);  b2 = fmaf(r2, x1, b2);
      }
    }
    for (; k < cnt; ++k){
      int j = __builtin_amdgcn_readlane(jv, k);
      float rj = __builtin_bit_cast(float, __builtin_amdgcn_readlane(rvb, k));
      float r2 = rj * rj;
      uint32_t hv = h[((uint32_t)j << 6) + lane];
      float x0 = __builtin_bit_cast(float, hv << 16);
      float x1 = __builtin_bit_cast(float, hv & 0xFFFF0000u);
      a0 += x0;               b0 += x1;
      a1 = fmaf(rj, x0, a1);  b1 = fmaf(rj, x1, b1);
      a2 = fmaf(r2, x0, a2);  b2 = fmaf(r2, x1, b2);
    }
  }
  size_t o = (size_t)wid * 64 + lane;
  P[o]  = pack2(a0, b0);
  T1[o] = pack2(a1, b1);
  T2[o] = pack2(a2, b2);
}

// Q1 = S(r.P), Q2 = S(r^2.P)
__launch_bounds__(256)
__global__ void k_spmmB(const int* __restrict__ col, const int* __restrict__ rp,
                        const float* __restrict__ r, const uint32_t* __restrict__ Pm,
                        uint32_t* __restrict__ Q1, uint32_t* __restrict__ Q2){
  int wid  = (blockIdx.x * blockDim.x + threadIdx.x) >> 6;
  int lane = threadIdx.x & 63;
  if (wid >= NN) return;
  int e0 = rp[wid], e1 = rp[wid + 1];
  float a1 = 0, b1 = 0, a2 = 0, b2 = 0;
  for (int base = e0; base < e1; base += 64){
    int tot = e1 - base;
    int cnt = tot < 64 ? tot : 64;
    int jv  = (lane < cnt) ? col[base + lane] : 0;
    int rvb = (lane < cnt) ? __builtin_bit_cast(int, r[jv]) : 0;
    int k = 0;
    for (; k + 16 <= cnt; k += 16){
      uint32_t pv[16];
      #pragma unroll
      for (int t = 0; t < 16; ++t){
        int j = __builtin_amdgcn_readlane(jv, k + t);
        pv[t] = Pm[((uint32_t)j << 6) + lane];
      }
      #pragma unroll
      for (int t = 0; t < 16; ++t){
        float rj = __builtin_bit_cast(float, __builtin_amdgcn_readlane(rvb, k + t));
        float r2 = rj * rj;
        float x0 = __builtin_bit_cast(float, pv[t] << 16);
        float x1 = __builtin_bit_cast(float, pv[t] & 0xFFFF0000u);
        a1 = fmaf(rj, x0, a1);  b1 = fmaf(rj, x1, b1);
        a2 = fmaf(r2, x0, a2);  b2 = fmaf(r2, x1, b2);
      }
    }
    for (; k + 4 <= cnt; k += 4){
      uint32_t pv[4];
      #pragma unroll
      for (int t = 0; t < 4; ++t){
        int j = __builtin_amdgcn_readlane(jv, k + t);
        pv[t] = Pm[((uint32_t)j << 6) + lane];
      }
      #pragma unroll
      for (int t = 0; t < 4; ++t){
        float rj = __builtin_bit_cast(float, __builtin_amdgcn_readlane(rvb, k + t));
        float r2 = rj * rj;
        float x0 = __builtin_bit_cast(float, pv[t] << 16);
        float x1 = __builtin_bit_cast(float, pv[t] & 0xFFFF0000u);
        a1 = fmaf(rj, x0, a1);  b1 = fmaf(rj, x1, b1);
        a2 = fmaf(r2, x0, a2);  b2 = fmaf(r2, x1, b2);
      }
    }
    for (; k < cnt; ++k){
      int j = __builtin_amdgcn_readlane(jv, k);
      float rj = __builtin_bit_cast(float, __builtin_amdgcn_readlane(rvb, k));
      float r2 = rj * rj;
      uint32_t pv = Pm[((uint32_t)j << 6) + lane];
      float x0 = __builtin_bit_cast(float, pv << 16);
      float x1 = __builtin_bit_cast(float, pv & 0xFFFF0000u);
      a1 = fmaf(rj, x0, a1);  b1 = fmaf(rj, x1, b1);
      a2 = fmaf(r2, x0, a2);  b2 = fmaf(r2, x1, b2);
    }
  }
  size_t o = (size_t)wid * 64 + lane;
  Q1[o] = pack2(a1, b1);
  Q2[o] = pack2(a2, b2);
}

// Epilogue v4: 512 threads (8 waves). Wave w owns col-tile w (16 cols) x 4
// row-tiles; A from LDS, B hoisted to regs per phase (epi2 dataflow).
// h,P held in regs for all layers; T/Q gathers issued one MFMA-phase early
// (T14 issue-early / use-late). Build: 8 threads/row, 2 x 16B chunks each.
__launch_bounds__(512, 4)
__global__ void k_epi4(const uint32_t* __restrict__ h,  const uint32_t* __restrict__ P,
                       const uint32_t* __restrict__ T1, const uint32_t* __restrict__ T2,
                       const uint32_t* __restrict__ Q1, const uint32_t* __restrict__ Q2,
                       const float* __restrict__ r,
                       const uint16_t* __restrict__ W1T, const uint16_t* __restrict__ W2T,
                       const uint16_t* __restrict__ Wl2T, const float* __restrict__ b2,
                       float* __restrict__ out){
  __shared__ __align__(16) uint32_t Mu[2][64][68];   // M1,M2 bf16 [64][136]
  const int tid = threadIdx.x;
  const int node0 = blockIdx.x * 64;
  const int wv = tid >> 6, lane = tid & 63, lr = lane & 15, lg = lane >> 4;

  // build ownership: 8 threads per row, chunks {qc, qc+8} (16B chunks of 16)
  const int nb = tid >> 3;
  const int qc = tid & 7;
  const int nd = node0 + nb;
  const int rn = nd < NN ? nd : NN - 1;
  const float rv = r[rn];
  const size_t ub = (size_t)rn * 64;
  const int cc2[2] = {qc, qc + 8};

  f32x4 acc[4];
  #pragma unroll
  for (int rt = 0; rt < 4; ++rt) acc[rt] = (f32x4){0.f, 0.f, 0.f, 0.f};

  // MFMA phase: B-frags hoisted to regs, A from LDS, no global in rt loop
  auto mfma_phase = [&](const uint16_t* Wa, const uint16_t* Wb){
    #pragma unroll
    for (int m = 0; m < 2; ++m){
      const uint16_t* bp = (m ? Wb : Wa) + (size_t)(wv * 16 + lr) * 128 + lg * 8;
      bf16x8 bfr[4];
      #pragma unroll
      for (int ks = 0; ks < 4; ++ks)
        bfr[ks] = __builtin_bit_cast(bf16x8, *(const uint4*)(bp + ks * 32));
      #pragma unroll
      for (int rt = 0; rt < 4; ++rt){
        const int row = rt * 16 + lr;
        f32x4 d = (f32x4){0.f, 0.f, 0.f, 0.f};
        #pragma unroll
        for (int ks = 0; ks < 4; ++ks){
          bf16x8 af = __builtin_bit_cast(bf16x8, *(const uint4*)&Mu[m][row][ks * 16 + lg * 4]);
          d = __builtin_amdgcn_mfma_f32_16x16x32_bf16(af, bfr[ks], d, 0, 0, 0);
        }
        #pragma unroll
        for (int q = 0; q < 4; ++q)
          acc[rt][q] += (d[q] > 0.f ? d[q] : 0.f);
      }
    }
  };

  // ---- persistent raw data: h, P (used by every layer) ----
  uint4 vh[2], vP[2];
  #pragma unroll
  for (int ci = 0; ci < 2; ++ci){
    vh[ci] = *(const uint4*)(h + ub + cc2[ci] * 4);
    vP[ci] = *(const uint4*)(P + ub + cc2[ci] * 4);
  }

  // ---- layer 0 build: M1 = F, M2 = h - F,  F = rv(p+h) ----
  #pragma unroll
  for (int ci = 0; ci < 2; ++ci){
    const uint32_t* ah = (const uint32_t*)&vh[ci];
    const uint32_t* ap = (const uint32_t*)&vP[ci];
    uint32_t o1[4], o2[4];
    #pragma unroll
    for (int w = 0; w < 4; ++w){
      float m1s[2], m2s[2];
      #pragma unroll
      for (int s = 0; s < 2; ++s){
        float hh = bf2f((uint16_t)(s ? (ah[w] >> 16) : ah[w]));
        float pp = bf2f((uint16_t)(s ? (ap[w] >> 16) : ap[w]));
        float F = rv * (pp + hh);
        m1s[s] = F; m2s[s] = hh - F;
      }
      o1[w] = pack2(m1s[0], m1s[1]);
      o2[w] = pack2(m2s[0], m2s[1]);
    }
    *(uint4*)&Mu[0][nb][cc2[ci] * 4] = make_uint4(o1[0], o1[1], o1[2], o1[3]);
    *(uint4*)&Mu[1][nb][cc2[ci] * 4] = make_uint4(o2[0], o2[1], o2[2], o2[3]);
  }
  // issue next layer's gathers BEFORE the barrier (latency hides under MFMA)
  uint4 vT1[2], vQ1[2];
  #pragma unroll
  for (int ci = 0; ci < 2; ++ci){
    vT1[ci] = *(const uint4*)(T1 + ub + cc2[ci] * 4);
    vQ1[ci] = *(const uint4*)(Q1 + ub + cc2[ci] * 4);
  }
  __syncthreads();
  mfma_phase(W1T, W2T);
  __syncthreads();

  // ---- layer 1 build ----
  #pragma unroll
  for (int ci = 0; ci < 2; ++ci){
    const uint32_t* ah = (const uint32_t*)&vh[ci];
    const uint32_t* ap = (const uint32_t*)&vP[ci];
    const uint32_t* at = (const uint32_t*)&vT1[ci];
    const uint32_t* aq = (const uint32_t*)&vQ1[ci];
    uint32_t o1[4], o2[4];
    #pragma unroll
    for (int w = 0; w < 4; ++w){
      float m1s[2], m2s[2];
      #pragma unroll
      for (int s = 0; s < 2; ++s){
        float hh = bf2f((uint16_t)(s ? (ah[w] >> 16) : ah[w]));
        float pp = bf2f((uint16_t)(s ? (ap[w] >> 16) : ap[w]));
        float t1 = bf2f((uint16_t)(s ? (at[w] >> 16) : at[w]));
        float q1 = bf2f((uint16_t)(s ? (aq[w] >> 16) : aq[w]));
        float F = rv * (pp + hh);
        float G = hh - F;
        m1s[s] = rv * (pp - q1 - t1 + G);
        m2s[s] = F - rv * (q1 + t1 + F);
      }
      o1[w] = pack2(m1s[0], m1s[1]);
      o2[w] = pack2(m2s[0], m2s[1]);
    }
    *(uint4*)&Mu[0][nb][cc2[ci] * 4] = make_uint4(o1[0], o1[1], o1[2], o1[3]);
    *(uint4*)&Mu[1][nb][cc2[ci] * 4] = make_uint4(o2[0], o2[1], o2[2], o2[3]);
  }
  uint4 vT2[2], vQ2[2];
  #pragma unroll
  for (int ci = 0; ci < 2; ++ci){
    vT2[ci] = *(const uint4*)(T2 + ub + cc2[ci] * 4);
    vQ2[ci] = *(const uint4*)(Q2 + ub + cc2[ci] * 4);
  }
  __syncthreads();
  mfma_phase(W1T + 16384, W2T + 16384);
  __syncthreads();

  // ---- layer 2 build ----
  #pragma unroll
  for (int ci = 0; ci < 2; ++ci){
    const uint32_t* ah = (const uint32_t*)&vh[ci];
    const uint32_t* ap = (const uint32_t*)&vP[ci];
    const uint32_t* at1 = (const uint32_t*)&vT1[ci];
    const uint32_t* at2 = (const uint32_t*)&vT2[ci];
    const uint32_t* aq2 = (const uint32_t*)&vQ2[ci];
    uint32_t o1[4], o2[4];
    #pragma unroll
    for (int w = 0; w < 4; ++w){
      float m1s[2], m2s[2];
      #pragma unroll
      for (int s = 0; s < 2; ++s){
        float hh = bf2f((uint16_t)(s ? (ah[w] >> 16) : ah[w]));
        float pp = bf2f((uint16_t)(s ? (ap[w] >> 16) : ap[w]));
        float t1 = bf2f((uint16_t)(s ? (at1[w] >> 16) : at1[w]));
        float t2 = bf2f((uint16_t)(s ? (at2[w] >> 16) : at2[w]));
        float q2 = bf2f((uint16_t)(s ? (aq2[w] >> 16) : aq2[w]));
        float omr = 1.f - rv;
        float G2 = rv * rv * pp + omr * omr * hh;
        m1s[s] = rv * (q2 + pp - 2.f * t1 + t2 + G2);
        float F2 = rv * rv * (pp + hh);
        m2s[s] = F2 - rv * (q2 + t2 + F2);
      }
      o1[w] = pack2(m1s[0], m1s[1]);
      o2[w] = pack2(m2s[0], m2s[1]);
    }
    *(uint4*)&Mu[0][nb][cc2[ci] * 4] = make_uint4(o1[0], o1[1], o1[2], o1[3]);
    *(uint4*)&Mu[1][nb][cc2[ci] * 4] = make_uint4(o2[0], o2[1], o2[2], o2[3]);
  }
  __syncthreads();
  mfma_phase(W1T + 2 * 16384, W2T + 2 * 16384);
  __syncthreads();

  // ---- layer 3 build ----
  #pragma unroll
  for (int ci = 0; ci < 2; ++ci){
    const uint32_t* ah = (const uint32_t*)&vh[ci];
    const uint32_t* ap = (const uint32_t*)&vP[ci];
    uint32_t o1[4], o2[4];
    #pragma unroll
    for (int w = 0; w < 4; ++w){
      float m1s[2], m2s[2];
      #pragma unroll
      for (int s = 0; s < 2; ++s){
        float hh = bf2f((uint16_t)(s ? (ah[w] >> 16) : ah[w]));
        float pp = bf2f((uint16_t)(s ? (ap[w] >> 16) : ap[w]));
        float omr = 1.f - rv;
        float r3 = rv * rv * rv;
        m1s[s] = omr * omr * omr * hh - r3 * pp;
        m2s[s] = r3 * (pp + hh);
      }
      o1[w] = pack2(m1s[0], m1s[1]);
      o2[w] = pack2(m2s[0], m2s[1]);
    }
    *(uint4*)&Mu[0][nb][cc2[ci] * 4] = make_uint4(o1[0], o1[1], o1[2], o1[3]);
    *(uint4*)&Mu[1][nb][cc2[ci] * 4] = make_uint4(o2[0], o2[1], o2[2], o2[3]);
  }
  __syncthreads();
  mfma_phase(W1T + 3 * 16384, W2T + 3 * 16384);
  __syncthreads();

  // ---- lin2: stage acc/8 as bf16 into Mu[0], then 64x128x64 MFMA ----
  uint16_t* Mb = (uint16_t*)&Mu[0][0][0];   // row stride 136 bf16 (68 uints)
  #pragma unroll
  for (int rt = 0; rt < 4; ++rt)
    #pragma unroll
    for (int q = 0; q < 4; ++q){
      int row = rt * 16 + lg * 4 + q;
      int colb = wv * 16 + lr;
      Mb[row * 136 + colb] = f2bf(acc[rt][q] * 0.125f);
    }
  __syncthreads();

  // wave w: row-tile w>>1, col-tiles {(w&1)*2, (w&1)*2+1}
  const int rt2 = wv >> 1;
  const int arow = rt2 * 16 + lr;
  bf16x8 af2[4];
  #pragma unroll
  for (int ks = 0; ks < 4; ++ks)
    af2[ks] = __builtin_bit_cast(bf16x8, *(const uint4*)&Mu[0][arow][ks * 16 + lg * 4]);
  #pragma unroll
  for (int ntl = 0; ntl < 2; ++ntl){
    const int nt = (wv & 1) * 2 + ntl;
    f32x4 d = (f32x4){0.f, 0.f, 0.f, 0.f};
    #pragma unroll
    for (int ks = 0; ks < 4; ++ks){
      bf16x8 bfr = __builtin_bit_cast(bf16x8,
          *(const uint4*)(Wl2T + (size_t)(nt * 16 + lr) * 128 + ks * 32 + lg * 8));
      d = __builtin_amdgcn_mfma_f32_16x16x32_bf16(af2[ks], bfr, d, 0, 0, 0);
    }
    float bias = b2[nt * 16 + lr];
    #pragma unroll
    for (int q = 0; q < 4; ++q){
      int rr = node0 + rt2 * 16 + lg * 4 + q;
      if (rr < NN) out[(size_t)rr * OUTF + nt * 16 + lr] = d[q] + bias;
    }
  }
}

extern "C" void kernel_launch(void* const* d_in, const int* in_sizes, int n_in,
                              void* d_out, int out_size, void* d_ws, size_t ws_size,
                              hipStream_t stream){
  const float* x   = (const float*)d_in[0];
  const float* Wl1 = (const float*)d_in[1];
  const float* bl1 = (const float*)d_in[2];
  const float* W1  = (const float*)d_in[3];
  const float* W2  = (const float*)d_in[4];
  const float* Wl2 = (const float*)d_in[5];
  const float* bl2 = (const float*)d_in[6];
  const int*   ei  = (const int*)d_in[7];
  int E = in_sizes[7] / 2;
  const int* rowp = ei;
  const int* colp = ei + E;

  char* ws = (char*)d_ws;
  size_t off = 0;
  auto alloc = [&](size_t bytes) -> void* {
    void* p = ws + off;
    off += (bytes + 255) & ~(size_t)255;
    return p;
  };
  const size_t MATB = (size_t)NN * HID * 2;
  uint32_t* h  = (uint32_t*)alloc(MATB);
  uint32_t* P  = (uint32_t*)alloc(MATB);
  uint32_t* T1 = (uint32_t*)alloc(MATB);
  uint32_t* T2 = (uint32_t*)alloc(MATB);
  uint32_t* Q1 = (uint32_t*)alloc(MATB);
  uint32_t* Q2 = (uint32_t*)alloc(MATB);
  float* r  = (float*)alloc((size_t)NN * 4);
  int* rp   = (int*)alloc((size_t)(NN + 1) * 4);
  uint16_t* W1T  = (uint16_t*)alloc((size_t)4 * 128 * 128 * 2);
  uint16_t* W2T  = (uint16_t*)alloc((size_t)4 * 128 * 128 * 2);
  uint16_t* Wl1T = (uint16_t*)alloc((size_t)128 * 256 * 2);
  uint16_t* Wl2T = (uint16_t*)alloc((size_t)64 * 128 * 2);

  k_wprep<<<(4 * 128 * 128 + 255) / 256, 256, 0, stream>>>(W1, W2, Wl1, Wl2,
                                                           W1T, W2T, Wl1T, Wl2T);
  k_csr<<<(NN + 1 + 255) / 256, 256, 0, stream>>>(rowp, E, NN, rp, r);
  k_lin1m<<<(NN + 63) / 64, 256, 0, stream>>>(x, Wl1T, bl1, (uint16_t*)h);
  k_spmmA<<<(NN + 3) / 4, 256, 0, stream>>>(colp, rp, r, h, P, T1, T2);
  k_spmmB<<<(NN + 3) / 4, 256, 0, stream>>>(colp, rp, r, P, Q1, Q2);
  k_epi4<<<(NN + 63) / 64, 512, 0, stream>>>(h, P, T1, T2, Q1, Q2, r,
                                             W1T, W2T, Wl2T, bl2, (float*)d_out);
}

// Round 8
// 403.142 us; speedup vs baseline: 1.3576x; 1.2592x over previous
//
#include <hip/hip_runtime.h>
#include <hip/hip_bf16.h>
#include <stdint.h>

#define NN   100000
#define ICH  256
#define HID  128
#define OUTF 64

typedef float  f32x4  __attribute__((ext_vector_type(4)));
typedef __bf16 bf16x8 __attribute__((ext_vector_type(8)));

__device__ __forceinline__ float bf2f(uint16_t u){
  union { uint32_t i; float f; } v; v.i = ((uint32_t)u) << 16; return v.f;
}
__device__ __forceinline__ uint16_t f2bf(float f){
  union { float f; uint32_t i; } v; v.f = f;
  uint32_t i = v.i;
  return (uint16_t)((i + 0x7FFFu + ((i >> 16) & 1u)) >> 16);
}
__device__ __forceinline__ uint32_t pack2(float a, float b){
  return (uint32_t)f2bf(a) | ((uint32_t)f2bf(b) << 16);
}

// Fused CSR build: edges sorted by src. rp[i] + r[i] = 1/(deg_i+1).
__global__ void k_csr(const int* __restrict__ row, int E, int n,
                      int* __restrict__ rp, float* __restrict__ r){
  int i = blockIdx.x * blockDim.x + threadIdx.x;
  if (i > n) return;
  int lo = 0, hi = E;
  while (lo < hi){
    int mid = (lo + hi) >> 1;
    if (row[mid] < i) lo = mid + 1; else hi = mid;
  }
  rp[i] = lo;
  if (i < n){
    int lo2 = lo, hi2 = E;
    while (lo2 < hi2){
      int mid = (lo2 + hi2) >> 1;
      if (row[mid] < i + 1) lo2 = mid + 1; else hi2 = mid;
    }
    r[i] = 1.0f / (float)(lo2 - lo + 1);
  }
}

// bf16-transpose weights: W1T/W2T [l][n][k], Wl1T [n][k] (k<256), Wl2T [n][k]
__global__ void k_wprep(const float* __restrict__ W1, const float* __restrict__ W2,
                        const float* __restrict__ Wl1, const float* __restrict__ Wl2,
                        uint16_t* __restrict__ W1T, uint16_t* __restrict__ W2T,
                        uint16_t* __restrict__ Wl1T, uint16_t* __restrict__ Wl2T){
  int idx = blockIdx.x * blockDim.x + threadIdx.x;
  if (idx < 4 * 128 * 128){
    int l = idx >> 14, rem = idx & 16383, n = rem >> 7, k = rem & 127;
    W1T[idx] = f2bf(W1[l * 16384 + k * 128 + n]);
    W2T[idx] = f2bf(W2[l * 16384 + k * 128 + n]);
  }
  if (idx < 128 * 256){
    int n = idx >> 8, k = idx & 255;
    Wl1T[idx] = f2bf(Wl1[k * 128 + n]);
  }
  if (idx < 64 * 128){
    int n = idx >> 7, k = idx & 127;
    Wl2T[idx] = f2bf(Wl2[k * 64 + n]);
  }
}

// h = relu(x @ W_lin1 + b) via MFMA. 64-node tile, wave w owns cols [32w,32w+32).
__launch_bounds__(256)
__global__ void k_lin1m(const float* __restrict__ x, const uint16_t* __restrict__ Wl1T,
                        const float* __restrict__ b, uint16_t* __restrict__ h){
  __shared__ __align__(16) uint16_t Xs[64][264];   // 256 + 8 pad
  const int tid = threadIdx.x;
  const int node0 = blockIdx.x * 64;
  const int wv = tid >> 6, lane = tid & 63, lr = lane & 15, lg = lane >> 4;

  #pragma unroll
  for (int i = 0; i < 16; ++i){
    int fi = tid + i * 256;
    int rrow = fi >> 6, c4 = (fi & 63) * 4;
    int nd = node0 + rrow;
    float4 f = (nd < NN) ? *(const float4*)(x + (size_t)nd * ICH + c4)
                         : make_float4(0.f, 0.f, 0.f, 0.f);
    *(uint2*)&Xs[rrow][c4] = make_uint2(pack2(f.x, f.y), pack2(f.z, f.w));
  }
  __syncthreads();

  bf16x8 bfr[2][8];
  #pragma unroll
  for (int n2 = 0; n2 < 2; ++n2){
    const int n = (2 * wv + n2) * 16 + lr;
    const uint16_t* bp = Wl1T + (size_t)n * 256 + lg * 8;
    #pragma unroll
    for (int ks = 0; ks < 8; ++ks)
      bfr[n2][ks] = __builtin_bit_cast(bf16x8, *(const uint4*)(bp + ks * 32));
  }
  float bias[2] = {b[(2 * wv + 0) * 16 + lr], b[(2 * wv + 1) * 16 + lr]};

  #pragma unroll
  for (int rt = 0; rt < 4; ++rt){
    const int row = rt * 16 + lr;
    bf16x8 af[8];
    #pragma unroll
    for (int ks = 0; ks < 8; ++ks)
      af[ks] = __builtin_bit_cast(bf16x8, *(const uint4*)&Xs[row][ks * 32 + lg * 8]);
    #pragma unroll
    for (int n2 = 0; n2 < 2; ++n2){
      f32x4 d = (f32x4){0.f, 0.f, 0.f, 0.f};
      #pragma unroll
      for (int ks = 0; ks < 8; ++ks)
        d = __builtin_amdgcn_mfma_f32_16x16x32_bf16(af[ks], bfr[n2][ks], d, 0, 0, 0);
      const int ncol = (2 * wv + n2) * 16 + lr;
      #pragma unroll
      for (int q = 0; q < 4; ++q){
        int nd = node0 + rt * 16 + lg * 4 + q;
        if (nd < NN){
          float v = d[q] + bias[n2];
          h[(size_t)nd * HID + ncol] = f2bf(v > 0.f ? v : 0.f);
        }
      }
    }
  }
}

// one wave per node: P = S h, T1 = S(r.h), T2 = S(r^2.h)
__launch_bounds__(256)
__global__ void k_spmmA(const int* __restrict__ col, const int* __restrict__ rp,
                        const float* __restrict__ r, const uint32_t* __restrict__ h,
                        uint32_t* __restrict__ P, uint32_t* __restrict__ T1,
                        uint32_t* __restrict__ T2){
  int wid  = (blockIdx.x * blockDim.x + threadIdx.x) >> 6;
  int lane = threadIdx.x & 63;
  if (wid >= NN) return;
  int e0 = rp[wid], e1 = rp[wid + 1];
  float a0 = 0, b0 = 0, a1 = 0, b1 = 0, a2 = 0, b2 = 0;
  for (int base = e0; base < e1; base += 64){
    int tot = e1 - base;
    int cnt = tot < 64 ? tot : 64;
    int jv  = (lane < cnt) ? col[base + lane] : 0;
    int rvb = (lane < cnt) ? __builtin_bit_cast(int, r[jv]) : 0;
    int k = 0;
    for (; k + 16 <= cnt; k += 16){
      uint32_t hv[16];
      #pragma unroll
      for (int t = 0; t < 16; ++t){
        int j = __builtin_amdgcn_readlane(jv, k + t);
        hv[t] = h[((uint32_t)j << 6) + lane];
      }
      #pragma unroll
      for (int t = 0; t < 16; ++t){
        float rj = __builtin_bit_cast(float, __builtin_amdgcn_readlane(rvb, k + t));
        float r2 = rj * rj;
        float x0 = __builtin_bit_cast(float, hv[t] << 16);
        float x1 = __builtin_bit_cast(float, hv[t] & 0xFFFF0000u);
        a0 += x0;               b0 += x1;
        a1 = fmaf(rj, x0, a1);  b1 = fmaf(rj, x1, b1);
        a2 = fmaf(r2, x0, a2);  b2 = fmaf(r2, x1, b2);
      }
    }
    for (; k + 4 <= cnt; k += 4){
      uint32_t hv[4];
      #pragma unroll
      for (int t = 0; t < 4; ++t){
        int j = __builtin_amdgcn_readlane(jv, k + t);
        hv[t] = h[((uint32_t)j << 6) + lane];
      }
      #pragma unroll
      for (int t = 0; t < 4; ++t){
        float rj = __builtin_bit_cast(float, __builtin_amdgcn_readlane(rvb, k + t));
        float r2 = rj * rj;
        float x0 = __builtin_bit_cast(float, hv[t] << 16);
        float x1 = __builtin_bit_cast(float, hv[t] & 0xFFFF0000u);
        a0 += x0;               b0 += x1;
        a1 = fmaf(rj, x0, a1);  b1 = fmaf(rj, x1, b1);
        a2 = fmaf(r2, x0, a2);  b2 = fmaf(r2, x1, b2);
      }
    }
    for (; k < cnt; ++k){
      int j = __builtin_amdgcn_readlane(jv, k);
      float rj = __builtin_bit_cast(float, __builtin_amdgcn_readlane(rvb, k));
      float r2 = rj * rj;
      uint32_t hv = h[((uint32_t)j << 6) + lane];
      float x0 = __builtin_bit_cast(float, hv << 16);
      float x1 = __builtin_bit_cast(float, hv & 0xFFFF0000u);
      a0 += x0;               b0 += x1;
      a1 = fmaf(rj, x0, a1);  b1 = fmaf(rj, x1, b1);
      a2 = fmaf(r2, x0, a2);  b2 = fmaf(r2, x1, b2);
    }
  }
  size_t o = (size_t)wid * 64 + lane;
  P[o]  = pack2(a0, b0);
  T1[o] = pack2(a1, b1);
  T2[o] = pack2(a2, b2);
}

// Q1 = S(r.P), Q2 = S(r^2.P)
__launch_bounds__(256)
__global__ void k_spmmB(const int* __restrict__ col, const int* __restrict__ rp,
                        const float* __restrict__ r, const uint32_t* __restrict__ Pm,
                        uint32_t* __restrict__ Q1, uint32_t* __restrict__ Q2){
  int wid  = (blockIdx.x * blockDim.x + threadIdx.x) >> 6;
  int lane = threadIdx.x & 63;
  if (wid >= NN) return;
  int e0 = rp[wid], e1 = rp[wid + 1];
  float a1 = 0, b1 = 0, a2 = 0, b2 = 0;
  for (int base = e0; base < e1; base += 64){
    int tot = e1 - base;
    int cnt = tot < 64 ? tot : 64;
    int jv  = (lane < cnt) ? col[base + lane] : 0;
    int rvb = (lane < cnt) ? __builtin_bit_cast(int, r[jv]) : 0;
    int k = 0;
    for (; k + 16 <= cnt; k += 16){
      uint32_t pv[16];
      #pragma unroll
      for (int t = 0; t < 16; ++t){
        int j = __builtin_amdgcn_readlane(jv, k + t);
        pv[t] = Pm[((uint32_t)j << 6) + lane];
      }
      #pragma unroll
      for (int t = 0; t < 16; ++t){
        float rj = __builtin_bit_cast(float, __builtin_amdgcn_readlane(rvb, k + t));
        float r2 = rj * rj;
        float x0 = __builtin_bit_cast(float, pv[t] << 16);
        float x1 = __builtin_bit_cast(float, pv[t] & 0xFFFF0000u);
        a1 = fmaf(rj, x0, a1);  b1 = fmaf(rj, x1, b1);
        a2 = fmaf(r2, x0, a2);  b2 = fmaf(r2, x1, b2);
      }
    }
    for (; k + 4 <= cnt; k += 4){
      uint32_t pv[4];
      #pragma unroll
      for (int t = 0; t < 4; ++t){
        int j = __builtin_amdgcn_readlane(jv, k + t);
        pv[t] = Pm[((uint32_t)j << 6) + lane];
      }
      #pragma unroll
      for (int t = 0; t < 4; ++t){
        float rj = __builtin_bit_cast(float, __builtin_amdgcn_readlane(rvb, k + t));
        float r2 = rj * rj;
        float x0 = __builtin_bit_cast(float, pv[t] << 16);
        float x1 = __builtin_bit_cast(float, pv[t] & 0xFFFF0000u);
        a1 = fmaf(rj, x0, a1);  b1 = fmaf(rj, x1, b1);
        a2 = fmaf(r2, x0, a2);  b2 = fmaf(r2, x1, b2);
      }
    }
    for (; k < cnt; ++k){
      int j = __builtin_amdgcn_readlane(jv, k);
      float rj = __builtin_bit_cast(float, __builtin_amdgcn_readlane(rvb, k));
      float r2 = rj * rj;
      uint32_t pv = Pm[((uint32_t)j << 6) + lane];
      float x0 = __builtin_bit_cast(float, pv << 16);
      float x1 = __builtin_bit_cast(float, pv & 0xFFFF0000u);
      a1 = fmaf(rj, x0, a1);  b1 = fmaf(rj, x1, b1);
      a2 = fmaf(r2, x0, a2);  b2 = fmaf(r2, x1, b2);
    }
  }
  size_t o = (size_t)wid * 64 + lane;
  Q1[o] = pack2(a1, b1);
  Q2[o] = pack2(a2, b2);
}

// Epilogue v5: epi4 geometry (512 thr, wave w -> 16-col tile x 4 row-tiles,
// A via LDS, B hoisted to regs) WITHOUT the VGPR cap that caused epi4's
// spills. Prefetch schedule trimmed so peak live state ~5 uint4-pairs.
__launch_bounds__(512)
__global__ void k_epi5(const uint32_t* __restrict__ h,  const uint32_t* __restrict__ P,
                       const uint32_t* __restrict__ T1, const uint32_t* __restrict__ T2,
                       const uint32_t* __restrict__ Q1, const uint32_t* __restrict__ Q2,
                       const float* __restrict__ r,
                       const uint16_t* __restrict__ W1T, const uint16_t* __restrict__ W2T,
                       const uint16_t* __restrict__ Wl2T, const float* __restrict__ b2,
                       float* __restrict__ out){
  __shared__ __align__(16) uint32_t Mu[2][64][68];   // M1,M2 bf16 [64][136]
  const int tid = threadIdx.x;
  const int node0 = blockIdx.x * 64;
  const int wv = tid >> 6, lane = tid & 63, lr = lane & 15, lg = lane >> 4;

  // build ownership: 8 threads per row, chunks {qc, qc+8}
  const int nb = tid >> 3;
  const int qc = tid & 7;
  const int nd = node0 + nb;
  const int rn = nd < NN ? nd : NN - 1;
  const float rv = r[rn];
  const size_t ub = (size_t)rn * 64;
  const int cc2[2] = {qc, qc + 8};

  f32x4 acc[4];
  #pragma unroll
  for (int rt = 0; rt < 4; ++rt) acc[rt] = (f32x4){0.f, 0.f, 0.f, 0.f};

  auto mfma_phase = [&](const uint16_t* Wa, const uint16_t* Wb){
    #pragma unroll
    for (int m = 0; m < 2; ++m){
      const uint16_t* bp = (m ? Wb : Wa) + (size_t)(wv * 16 + lr) * 128 + lg * 8;
      bf16x8 bfr[4];
      #pragma unroll
      for (int ks = 0; ks < 4; ++ks)
        bfr[ks] = __builtin_bit_cast(bf16x8, *(const uint4*)(bp + ks * 32));
      #pragma unroll
      for (int rt = 0; rt < 4; ++rt){
        const int row = rt * 16 + lr;
        f32x4 d = (f32x4){0.f, 0.f, 0.f, 0.f};
        #pragma unroll
        for (int ks = 0; ks < 4; ++ks){
          bf16x8 af = __builtin_bit_cast(bf16x8, *(const uint4*)&Mu[m][row][ks * 16 + lg * 4]);
          d = __builtin_amdgcn_mfma_f32_16x16x32_bf16(af, bfr[ks], d, 0, 0, 0);
        }
        #pragma unroll
        for (int q = 0; q < 4; ++q)
          acc[rt][q] += (d[q] > 0.f ? d[q] : 0.f);
      }
    }
  };

  // persistent h,P + early prefetch of T1,Q1 (in flight under layer-0 work)
  uint4 vh[2], vP[2], vT1[2], vQ1[2];
  #pragma unroll
  for (int ci = 0; ci < 2; ++ci){
    vh[ci]  = *(const uint4*)(h  + ub + cc2[ci] * 4);
    vP[ci]  = *(const uint4*)(P  + ub + cc2[ci] * 4);
    vT1[ci] = *(const uint4*)(T1 + ub + cc2[ci] * 4);
    vQ1[ci] = *(const uint4*)(Q1 + ub + cc2[ci] * 4);
  }

  // ---- layer 0 build ----
  #pragma unroll
  for (int ci = 0; ci < 2; ++ci){
    const uint32_t* ah = (const uint32_t*)&vh[ci];
    const uint32_t* ap = (const uint32_t*)&vP[ci];
    uint32_t o1[4], o2[4];
    #pragma unroll
    for (int w = 0; w < 4; ++w){
      float m1s[2], m2s[2];
      #pragma unroll
      for (int s = 0; s < 2; ++s){
        float hh = bf2f((uint16_t)(s ? (ah[w] >> 16) : ah[w]));
        float pp = bf2f((uint16_t)(s ? (ap[w] >> 16) : ap[w]));
        float F = rv * (pp + hh);
        m1s[s] = F; m2s[s] = hh - F;
      }
      o1[w] = pack2(m1s[0], m1s[1]);
      o2[w] = pack2(m2s[0], m2s[1]);
    }
    *(uint4*)&Mu[0][nb][cc2[ci] * 4] = make_uint4(o1[0], o1[1], o1[2], o1[3]);
    *(uint4*)&Mu[1][nb][cc2[ci] * 4] = make_uint4(o2[0], o2[1], o2[2], o2[3]);
  }
  __syncthreads();
  mfma_phase(W1T, W2T);
  __syncthreads();

  // ---- layer 1 build (consumes Q1; T1 stays live for layer 2) ----
  #pragma unroll
  for (int ci = 0; ci < 2; ++ci){
    const uint32_t* ah = (const uint32_t*)&vh[ci];
    const uint32_t* ap = (const uint32_t*)&vP[ci];
    const uint32_t* at = (const uint32_t*)&vT1[ci];
    const uint32_t* aq = (const uint32_t*)&vQ1[ci];
    uint32_t o1[4], o2[4];
    #pragma unroll
    for (int w = 0; w < 4; ++w){
      float m1s[2], m2s[2];
      #pragma unroll
      for (int s = 0; s < 2; ++s){
        float hh = bf2f((uint16_t)(s ? (ah[w] >> 16) : ah[w]));
        float pp = bf2f((uint16_t)(s ? (ap[w] >> 16) : ap[w]));
        float t1 = bf2f((uint16_t)(s ? (at[w] >> 16) : at[w]));
        float q1 = bf2f((uint16_t)(s ? (aq[w] >> 16) : aq[w]));
        float F = rv * (pp + hh);
        float G = hh - F;
        m1s[s] = rv * (pp - q1 - t1 + G);
        m2s[s] = F - rv * (q1 + t1 + F);
      }
      o1[w] = pack2(m1s[0], m1s[1]);
      o2[w] = pack2(m2s[0], m2s[1]);
    }
    *(uint4*)&Mu[0][nb][cc2[ci] * 4] = make_uint4(o1[0], o1[1], o1[2], o1[3]);
    *(uint4*)&Mu[1][nb][cc2[ci] * 4] = make_uint4(o2[0], o2[1], o2[2], o2[3]);
  }
  // Q1 dead -> prefetch T2,Q2 now; latency hides under layer-1 MFMA phase
  uint4 vT2[2], vQ2[2];
  #pragma unroll
  for (int ci = 0; ci < 2; ++ci){
    vT2[ci] = *(const uint4*)(T2 + ub + cc2[ci] * 4);
    vQ2[ci] = *(const uint4*)(Q2 + ub + cc2[ci] * 4);
  }
  __syncthreads();
  mfma_phase(W1T + 16384, W2T + 16384);
  __syncthreads();

  // ---- layer 2 build ----
  #pragma unroll
  for (int ci = 0; ci < 2; ++ci){
    const uint32_t* ah = (const uint32_t*)&vh[ci];
    const uint32_t* ap = (const uint32_t*)&vP[ci];
    const uint32_t* at1 = (const uint32_t*)&vT1[ci];
    const uint32_t* at2 = (const uint32_t*)&vT2[ci];
    const uint32_t* aq2 = (const uint32_t*)&vQ2[ci];
    uint32_t o1[4], o2[4];
    #pragma unroll
    for (int w = 0; w < 4; ++w){
      float m1s[2], m2s[2];
      #pragma unroll
      for (int s = 0; s < 2; ++s){
        float hh = bf2f((uint16_t)(s ? (ah[w] >> 16) : ah[w]));
        float pp = bf2f((uint16_t)(s ? (ap[w] >> 16) : ap[w]));
        float t1 = bf2f((uint16_t)(s ? (at1[w] >> 16) : at1[w]));
        float t2 = bf2f((uint16_t)(s ? (at2[w] >> 16) : at2[w]));
        float q2 = bf2f((uint16_t)(s ? (aq2[w] >> 16) : aq2[w]));
        float omr = 1.f - rv;
        float G2 = rv * rv * pp + omr * omr * hh;
        m1s[s] = rv * (q2 + pp - 2.f * t1 + t2 + G2);
        float F2 = rv * rv * (pp + hh);
        m2s[s] = F2 - rv * (q2 + t2 + F2);
      }
      o1[w] = pack2(m1s[0], m1s[1]);
      o2[w] = pack2(m2s[0], m2s[1]);
    }
    *(uint4*)&Mu[0][nb][cc2[ci] * 4] = make_uint4(o1[0], o1[1], o1[2], o1[3]);
    *(uint4*)&Mu[1][nb][cc2[ci] * 4] = make_uint4(o2[0], o2[1], o2[2], o2[3]);
  }
  __syncthreads();
  mfma_phase(W1T + 2 * 16384, W2T + 2 * 16384);
  __syncthreads();

  // ---- layer 3 build ----
  #pragma unroll
  for (int ci = 0; ci < 2; ++ci){
    const uint32_t* ah = (const uint32_t*)&vh[ci];
    const uint32_t* ap = (const uint32_t*)&vP[ci];
    uint32_t o1[4], o2[4];
    #pragma unroll
    for (int w = 0; w < 4; ++w){
      float m1s[2], m2s[2];
      #pragma unroll
      for (int s = 0; s < 2; ++s){
        float hh = bf2f((uint16_t)(s ? (ah[w] >> 16) : ah[w]));
        float pp = bf2f((uint16_t)(s ? (ap[w] >> 16) : ap[w]));
        float omr = 1.f - rv;
        float r3 = rv * rv * rv;
        m1s[s] = omr * omr * omr * hh - r3 * pp;
        m2s[s] = r3 * (pp + hh);
      }
      o1[w] = pack2(m1s[0], m1s[1]);
      o2[w] = pack2(m2s[0], m2s[1]);
    }
    *(uint4*)&Mu[0][nb][cc2[ci] * 4] = make_uint4(o1[0], o1[1], o1[2], o1[3]);
    *(uint4*)&Mu[1][nb][cc2[ci] * 4] = make_uint4(o2[0], o2[1], o2[2], o2[3]);
  }
  __syncthreads();
  mfma_phase(W1T + 3 * 16384, W2T + 3 * 16384);
  __syncthreads();

  // ---- lin2: stage acc/8 as bf16 into Mu[0], then 64x128x64 MFMA ----
  uint16_t* Mb = (uint16_t*)&Mu[0][0][0];
  #pragma unroll
  for (int rt = 0; rt < 4; ++rt)
    #pragma unroll
    for (int q = 0; q < 4; ++q){
      int row = rt * 16 + lg * 4 + q;
      int colb = wv * 16 + lr;
      Mb[row * 136 + colb] = f2bf(acc[rt][q] * 0.125f);
    }
  __syncthreads();

  const int rt2 = wv >> 1;
  const int arow = rt2 * 16 + lr;
  bf16x8 af2[4];
  #pragma unroll
  for (int ks = 0; ks < 4; ++ks)
    af2[ks] = __builtin_bit_cast(bf16x8, *(const uint4*)&Mu[0][arow][ks * 16 + lg * 4]);
  #pragma unroll
  for (int ntl = 0; ntl < 2; ++ntl){
    const int nt = (wv & 1) * 2 + ntl;
    f32x4 d = (f32x4){0.f, 0.f, 0.f, 0.f};
    #pragma unroll
    for (int ks = 0; ks < 4; ++ks){
      bf16x8 bfr = __builtin_bit_cast(bf16x8,
          *(const uint4*)(Wl2T + (size_t)(nt * 16 + lr) * 128 + ks * 32 + lg * 8));
      d = __builtin_amdgcn_mfma_f32_16x16x32_bf16(af2[ks], bfr, d, 0, 0, 0);
    }
    float bias = b2[nt * 16 + lr];
    #pragma unroll
    for (int q = 0; q < 4; ++q){
      int rr = node0 + rt2 * 16 + lg * 4 + q;
      if (rr < NN) out[(size_t)rr * OUTF + nt * 16 + lr] = d[q] + bias;
    }
  }
}

extern "C" void kernel_launch(void* const* d_in, const int* in_sizes, int n_in,
                              void* d_out, int out_size, void* d_ws, size_t ws_size,
                              hipStream_t stream){
  const float* x   = (const float*)d_in[0];
  const float* Wl1 = (const float*)d_in[1];
  const float* bl1 = (const float*)d_in[2];
  const float* W1  = (const float*)d_in[3];
  const float* W2  = (const float*)d_in[4];
  const float* Wl2 = (const float*)d_in[5];
  const float* bl2 = (const float*)d_in[6];
  const int*   ei  = (const int*)d_in[7];
  int E = in_sizes[7] / 2;
  const int* rowp = ei;
  const int* colp = ei + E;

  char* ws = (char*)d_ws;
  size_t off = 0;
  auto alloc = [&](size_t bytes) -> void* {
    void* p = ws + off;
    off += (bytes + 255) & ~(size_t)255;
    return p;
  };
  const size_t MATB = (size_t)NN * HID * 2;
  uint32_t* h  = (uint32_t*)alloc(MATB);
  uint32_t* P  = (uint32_t*)alloc(MATB);
  uint32_t* T1 = (uint32_t*)alloc(MATB);
  uint32_t* T2 = (uint32_t*)alloc(MATB);
  uint32_t* Q1 = (uint32_t*)alloc(MATB);
  uint32_t* Q2 = (uint32_t*)alloc(MATB);
  float* r  = (float*)alloc((size_t)NN * 4);
  int* rp   = (int*)alloc((size_t)(NN + 1) * 4);
  uint16_t* W1T  = (uint16_t*)alloc((size_t)4 * 128 * 128 * 2);
  uint16_t* W2T  = (uint16_t*)alloc((size_t)4 * 128 * 128 * 2);
  uint16_t* Wl1T = (uint16_t*)alloc((size_t)128 * 256 * 2);
  uint16_t* Wl2T = (uint16_t*)alloc((size_t)64 * 128 * 2);

  k_wprep<<<(4 * 128 * 128 + 255) / 256, 256, 0, stream>>>(W1, W2, Wl1, Wl2,
                                                           W1T, W2T, Wl1T, Wl2T);
  k_csr<<<(NN + 1 + 255) / 256, 256, 0, stream>>>(rowp, E, NN, rp, r);
  k_lin1m<<<(NN + 63) / 64, 256, 0, stream>>>(x, Wl1T, bl1, (uint16_t*)h);
  k_spmmA<<<(NN + 3) / 4, 256, 0, stream>>>(colp, rp, r, h, P, T1, T2);
  k_spmmB<<<(NN + 3) / 4, 256, 0, stream>>>(colp, rp, r, P, Q1, Q2);
  k_epi5<<<(NN + 63) / 64, 512, 0, stream>>>(h, P, T1, T2, Q1, Q2, r,
                                             W1T, W2T, Wl2T, bl2, (float*)d_out);
}